// Round 14
// baseline (173.970 us; speedup 1.0000x reference)
//
#include <hip/hip_runtime.h>

// RelativePositionSDPA — R21: R20/R17 structure with Vt SINGLE-buffered —
// LDS 50192 -> 42000 B to probe for a 3rd resident block.
//
// Occupancy-pin re-analysis (13 rounds): the old "~124KB pool" model was
// confounded — R11's 2-block result had VGPR 116 (register-pinned). Clean
// reads: VGPR>=84 -> 2 blocks regardless of LDS; VGPR<=64 -> 3-4 blocks.
// R17/R20 (VGPR 80) were LDS-pinned at 2 (50.7K x3 > pool). The untested
// cell: LDS <= ~42K at VGPR 80. R21 tests it.
//
// Mechanism: V is read only in PV, and cross-wave visibility of the V tile
// needs a barrier anyway -> Vt single-buffered, V-DMA forced at barrier B.
// Wait schedule simplifies to ONE count: issue order per iter is
//   dmaV(k) [2], bandLoad [2], dmaK(k+1) [2]
// and barrier B waits vmcnt(4): forces prev-iter dmaK (Kb[cur]) AND this
// iter's dmaV; leaves band+dmaK(next) in flight. First iter: vmcnt(4) also
// forces the prologue pair (older). Last iter: vmcnt(0) (only dmaV issued).
// Exposure: ~200-400cy of V-DMA latency at barrier B, covered by the other
// resident block(s).
//
// Outcomes: (a) occupancy ~35% (3 blocks) -> main ~68-73us, win;
// (b) occupancy ~24% -> register pin at VGPR~80 definitive, structure boxed
// (cost ~3-5us), declare plateau next round.
//
// Everything else identical to R20/R17: DMA staging w=16 (linear LDS dest +
// pre-swizzled global src; Vt half-XOR baked in ws), swapped-operand QK^T,
// reg-direct PV (K=16 bf16), batched gather + mirror cols, deferred ring
// flush, setprio, C-init softmax shift, exp2 domain, RTN f16 ring pack.

#define SQ    1024
#define HD    64
#define NHD   16
#define RMAX  2048

typedef _Float16 f16x8 __attribute__((ext_vector_type(8)));
typedef _Float16 f16x4 __attribute__((ext_vector_type(4)));
typedef short    b16x8 __attribute__((ext_vector_type(8)));
typedef short    b16x4 __attribute__((ext_vector_type(4)));
typedef float    f32x4 __attribute__((ext_vector_type(4)));
typedef unsigned u32x2 __attribute__((ext_vector_type(2)));
typedef unsigned u32x4 __attribute__((ext_vector_type(4)));

#define MFMA_F16(A,B,C)  __builtin_amdgcn_mfma_f32_16x16x32_f16((A),(B),(C),0,0,0)
#define MFMA_BF16(A,B,C) __builtin_amdgcn_mfma_f32_16x16x32_bf16((A),(B),(C),0,0,0)

#define L2E    1.44269504088896f    // log2(e)
#define NSHIFT (-57.7078016f)       // -40 * log2(e)

// ws layout
#define KH_OFF   0                       // f16 [64][1024][64]   8 MB
#define VT_OFF   (8u << 20)              // bf16 [64][80][1024]  10 MB (half-XOR'd rows)
#define R16_OFF  (18u << 20)             // f16 [16][1024][64]   2 MB
#define WS_NEED  (20u << 20)

__device__ __forceinline__ float exp2fast(float x) {
#if __has_builtin(__builtin_amdgcn_exp2f)
  return __builtin_amdgcn_exp2f(x);          // v_exp_f32 (2^x native)
#else
  return __expf(x * 0.693147180559945f);
#endif
}

// K=16 bf16 MFMA; zero-padded K=32 fallback is mathematically identical.
__device__ __forceinline__ f32x4 mfma16bf(b16x4 a, b16x4 b, f32x4 c) {
#if __has_builtin(__builtin_amdgcn_mfma_f32_16x16x16bf16_1k)
  return __builtin_amdgcn_mfma_f32_16x16x16bf16_1k(a, b, c, 0, 0, 0);
#else
  b16x8 az = {a[0], a[1], a[2], a[3], 0, 0, 0, 0};
  b16x8 bz = {b[0], b[1], b[2], b[3], 0, 0, 0, 0};
  return MFMA_BF16(az, bz, c);
#endif
}

__device__ __forceinline__ short f2b(float f) {          // fp32 -> bf16 RTN-even
  unsigned u = __builtin_bit_cast(unsigned, f);
  u += 0x7FFFu + ((u >> 16) & 1u);
  return (short)(u >> 16);
}
// 2xf32 -> packed f16 RTN (scalar casts; champion numerics)
__device__ __forceinline__ unsigned pkh(float a, float b) {
  _Float16 h0 = (_Float16)a, h1 = (_Float16)b;
  return (unsigned)__builtin_bit_cast(unsigned short, h0)
       | ((unsigned)__builtin_bit_cast(unsigned short, h1) << 16);
}
// 2xf32 -> packed bf16, round-half-away (differs from RTN-even only on ties)
__device__ __forceinline__ unsigned pkb2(float a, float b) {
  unsigned ua = __builtin_bit_cast(unsigned, a) + 0x8000u;
  unsigned ub = __builtin_bit_cast(unsigned, b) + 0x8000u;
  return (ub & 0xFFFF0000u) | (ua >> 16);
}
// f16 half (sh=0 lo, sh=16 hi) of a packed u32 -> float
__device__ __forceinline__ float h2f(unsigned w, int sh) {
  return (float)__builtin_bit_cast(_Float16, (unsigned short)(w >> sh));
}
// XOR-swizzled element address inside a [rows][64] 2B-elem tile (Kb).
__device__ __forceinline__ int swz(int row, int col) {
  return row*64 + ((((col >> 3) ^ row) & 7) << 3) + (col & 7);
}
// Vt variant: + half-XOR with row bit3 (conflict-free b64 PV reads).
__device__ __forceinline__ int swzv(int row, int col) {
  return row*64 + ((((col >> 3) ^ row) & 7) << 3)
       + ((col & 7) ^ ((row & 8) >> 1));
}

// ---------------- merged precompute kernel (unchanged) ----------------
// Vt ws rows stored with half-XOR baked in (u32-granular ^4 on rows with
// bit3) so the main kernel's 16B DMA chunks deposit swzv() order directly.

__global__ __launch_bounds__(256) void preprep(
    const float* __restrict__ K, const float* __restrict__ R,
    const float* __restrict__ V,
    _Float16* __restrict__ Kh, _Float16* __restrict__ R16,
    short* __restrict__ Vt)
{
  __shared__ float t[64][65];
  const int bid = blockIdx.x, tid = threadIdx.x;
  if (bid < 1024) {
    const int n = bid >> 4, st = bid & 15;
    {
      const int row = tid >> 2, c0 = (tid & 3) * 16;
      const float* src = V + ((size_t)n * SQ + st * 64 + row) * HD + c0;
#pragma unroll
      for (int i = 0; i < 4; ++i) {
        float4 x = ((const float4*)src)[i];
        t[row][c0 + 4*i + 0] = x.x; t[row][c0 + 4*i + 1] = x.y;
        t[row][c0 + 4*i + 2] = x.z; t[row][c0 + 4*i + 3] = x.w;
      }
    }
    __syncthreads();
    {
      const int d = tid >> 2, s0 = (tid & 3) * 16;
      const int xo = (d & 8) ? 4 : 0;                 // half-XOR baked into ws
      short* dst = Vt + ((size_t)n * 80 + d) * SQ + st * 64 + s0;
#pragma unroll
      for (int i = 0; i < 8; ++i)
        *(unsigned*)(dst + (2*i ^ xo)) = pkb2(t[s0 + 2*i][d], t[s0 + 2*i + 1][d]);
    }
    if (tid < 64) {          // rows 64..79 unused by main; kept harmless
      const int s = st * 64 + tid;
      Vt[((size_t)n * 80 + 64) * SQ + s] = (short)0x3F80;
#pragma unroll
      for (int r = 65; r < 80; ++r) Vt[((size_t)n * 80 + r) * SQ + s] = 0;
    }
  } else {
    const int idx = (bid - 1024) * 256 + tid;            // float4 index
    const int nk4 = (64 * SQ * HD) / 4;                  // 1048576
    if (idx < nk4) {
      float4 v = ((const float4*)K)[idx];
      f16x4 o = { (_Float16)v.x, (_Float16)v.y, (_Float16)v.z, (_Float16)v.w };
      *(f16x4*)(Kh + 4 * (size_t)idx) = o;
    } else {
      int rr = idx - nk4;                                // < 262144
      int h  = rr >> 14, off = rr & 16383;               // 16384 float4/head
      float4 v = ((const float4*)R)[((size_t)h << 15) + off];
      f16x4 o = { (_Float16)v.x, (_Float16)v.y, (_Float16)v.z, (_Float16)v.w };
      *(f16x4*)(R16 + 4 * (((size_t)h << 14) + off)) = o;
    }
  }
}

// ---------------- main flash kernel (R21) ----------------

__global__ __launch_bounds__(256, 3) void relpos_sdpa_r21(
    const float* __restrict__ Q, const _Float16* __restrict__ Kh,
    const short* __restrict__ Vtg, const _Float16* __restrict__ R16,
    const float* __restrict__ Ub, const float* __restrict__ Vb,
    float* __restrict__ O)
{
  const int n    = blockIdx.x;
  const int h    = n & (NHD - 1);
  const int a0   = blockIdx.y * 64;
  const int tid  = threadIdx.x;
  const int lane = tid & 63, wave = tid >> 6;
  const int l15  = lane & 15, quad = lane >> 4;

  const float*    Qn  = Q   + (size_t)n * SQ * HD;
  const _Float16* Khn = Kh  + (size_t)n * SQ * HD;
  const short*    Vgn = Vtg + (size_t)n * 80 * SQ;
  const _Float16* Rh  = R16 + (size_t)h * SQ * HD;

  // LDS: Kb f16 [2][64][64] swz @ 0      (2 x 8192)
  //      Vt bf16 [64][64] swzv  @ 16384  (8192, SINGLE buffer)
  //      ring u32 [33][132]     @ 24576  (17424; cols 128..130 mirror 0..2)
  // total 42000 B -> 3 blocks/CU if pool+registers permit (the experiment).
  __shared__ __align__(16) char lds[42000];
  unsigned*       Pb2  = (unsigned*)(lds + 24576);
  const _Float16* Pb2h = (const _Float16*)Pb2;

  // DMA: linear LDS dest (slot = lane + 64*(2w+i)), pre-swizzled global src.
  auto gload16 = [&](const void* g, void* l) {
#if __has_builtin(__builtin_amdgcn_global_load_lds)
    __builtin_amdgcn_global_load_lds(
        (const __attribute__((address_space(1))) unsigned*)g,
        (__attribute__((address_space(3))) unsigned*)l, 16, 0, 0);
#else
    *(u32x4*)((char*)l + lane * 16) = *(const u32x4*)g;   // reg round-trip
#endif
  };
  auto dmaK = [&](int kk, int buf) {
    const int rb = lane >> 3;
    const int g  = (lane & 7) ^ ((lane >> 3) & 7);
    char* kdst = lds + buf * 8192;
#pragma unroll
    for (int i = 0; i < 2; ++i) {
      const int sub = 2*wave + i;
      const int r   = 8*sub + rb;
      gload16(Khn + (size_t)(kk + r) * HD + 8*g, kdst + sub * 1024);
    }
  };
  auto dmaV = [&](int kk) {
    const int rb = lane >> 3;
    const int g  = (lane & 7) ^ ((lane >> 3) & 7);
    char* vdst = lds + 16384;
#pragma unroll
    for (int i = 0; i < 2; ++i) {
      const int sub = 2*wave + i;
      const int r   = 8*sub + rb;
      gload16(Vgn + (size_t)r * SQ + kk + 8*g, vdst + sub * 1024);
    }
  };

  dmaV(0);        // V tile 0 (oldest vmem)
  dmaK(0, 0);     // K tile 0

  // ---- persistent q fragments, pre-scaled by log2(e) ----
  f16x8 quF[2], qvF[5][2];
#pragma unroll
  for (int ks = 0; ks < 2; ++ks) {
    const int db = ks * 32 + quad * 8;
    float ub[8], vb[8];
#pragma unroll
    for (int j = 0; j < 8; ++j) {
      ub[j] = Ub[h*HD + db + j] * L2E;
      vb[j] = Vb[h*HD + db + j] * L2E;
    }
    {
      const float* p = Qn + (size_t)(a0 + 16*wave + l15) * HD + db;
      float4 x0 = ((const float4*)p)[0], x1 = ((const float4*)p)[1];
      f16x8 f;
#pragma unroll
      for (int t = 0; t < 4; ++t) {
        f[t]   = (_Float16)((&x0.x)[t] * (0.125f * L2E) + ub[t]);
        f[t+4] = (_Float16)((&x1.x)[t] * (0.125f * L2E) + ub[t+4]);
      }
      quF[ks] = f;
    }
#pragma unroll
    for (int rt = 0; rt < 5; ++rt) {
      int row = a0 + 16*rt + l15; if (row > SQ-1) row = SQ-1;
      const float* p = Qn + (size_t)row * HD + db;
      float4 x0 = ((const float4*)p)[0], x1 = ((const float4*)p)[1];
      f16x8 f;
#pragma unroll
      for (int t = 0; t < 4; ++t) {
        f[t]   = (_Float16)((&x0.x)[t] * (0.125f * L2E) + vb[t]);
        f[t+4] = (_Float16)((&x1.x)[t] * (0.125f * L2E) + vb[t+4]);
      }
      qvF[rt][ks] = f;
    }
  }

  f32x4 Oacc[4], acc_l;
#pragma unroll
  for (int ct = 0; ct < 4; ++ct) Oacc[ct] = (f32x4){0.f, 0.f, 0.f, 0.f};
  acc_l = (f32x4){0.f, 0.f, 0.f, 0.f};

  const b16x4 ONESB = {(short)0x3F80, (short)0x3F80, (short)0x3F80, (short)0x3F80};

  // ---- band, split: bandLoad (issue R16 loads early) / bandMFMA (compute) ----
  unsigned ringW[9];
  int ringSlot, ringSlotN;
  f16x8 bB0, bB1;
  auto bandLoad = [&](int jstart) {
    const int c = jstart + 16*wave + l15;
    const int j = (c + 2048) & (SQ - 1);
    ringSlotN   = (c + 2048) & 127;
    const _Float16* rp = Rh + (size_t)j * HD + quad * 8;
    bB0 = *(const f16x8*)rp;
    bB1 = *(const f16x8*)(rp + 32);
  };
  auto bandMFMA = [&]() {
    ringSlot = ringSlotN;
    __builtin_amdgcn_s_setprio(1);
#pragma unroll
    for (int rt = 0; rt < 5; ++rt) {
      f32x4 acc = (f32x4){0.f, 0.f, 0.f, 0.f};
      acc = MFMA_F16(qvF[rt][0], bB0, acc);
      acc = MFMA_F16(qvF[rt][1], bB1, acc);
      if (rt < 4) {
        ringW[2*rt]     = pkh(acc[0], acc[1]);
        ringW[2*rt + 1] = pkh(acc[2], acc[3]);
      } else {
        ringW[8] = pkh(acc[0], acc[1]);   // row 64 (only quad 0's used)
      }
    }
    __builtin_amdgcn_s_setprio(0);
  };
  auto ringFlush = [&]() {
#pragma unroll
    for (int rt = 0; rt < 4; ++rt) {
      const int rp0 = 8*rt + 2*quad;                 // rows 16rt+4q .. +3
      Pb2[rp0*132 + ringSlot]       = ringW[2*rt];
      Pb2[(rp0 + 1)*132 + ringSlot] = ringW[2*rt + 1];
    }
    if (quad == 0) Pb2[32*132 + ringSlot] = ringW[8];
    if (ringSlot < 3) {                              // mirror cols 128..130
      const int ms = ringSlot + 128;
#pragma unroll
      for (int rt = 0; rt < 4; ++rt) {
        const int rp0 = 8*rt + 2*quad;
        Pb2[rp0*132 + ms]       = ringW[2*rt];
        Pb2[(rp0 + 1)*132 + ms] = ringW[2*rt + 1];
      }
      if (quad == 0) Pb2[32*132 + ms] = ringW[8];
    }
  };

  // prologue: fill all 128 ring slots for iter 0 (pre-loop, no races)
  bandLoad(-a0 - 65);  bandMFMA();  ringFlush();
  bandLoad(-a0 - 1);   bandMFMA();  ringFlush();

  const int iiB = 16*wave + 4*quad;
  const int iQ  = 16*wave + l15;          // this lane's q-local row (swapped)

  int cur = 0;
  for (int k0 = 0; k0 < SQ; k0 += 64) {
    const bool first = (k0 == 0);
    const bool last  = (k0 == SQ - 64);

    // ---- barrier A: prev compute's LDS reads (incl. PV of Vt) done ----
    __builtin_amdgcn_sched_barrier(0);
    asm volatile("s_waitcnt lgkmcnt(0)" ::: "memory");
    __builtin_amdgcn_s_barrier();
    __builtin_amdgcn_sched_barrier(0);

    if (!first) ringFlush();          // ring cols from prev iter's bandMFMA
    if (!first) dmaV(k0);             // V tile k -> single buffer (2 vmem)
    if (!last) {
      bandLoad(k0 + 64 - a0 - 1);     // 2 vmem
      dmaK(k0 + 64, cur ^ 1);         // 2 vmem -> other K buffer
    }
    __builtin_amdgcn_sched_barrier(0);
    // barrier B wait: force prev-iter dmaK (Kb[cur]) AND this iter's dmaV;
    // allow band(2)+dmaK(2) in flight. Last iter: only dmaV issued -> 0.
    if (!last) asm volatile("s_waitcnt vmcnt(4) lgkmcnt(0)" ::: "memory");
    else       asm volatile("s_waitcnt vmcnt(0) lgkmcnt(0)" ::: "memory");
    // ---- barrier B: Kb[cur] + Vt staged + ring visible ----
    __builtin_amdgcn_s_barrier();
    __builtin_amdgcn_sched_barrier(0);

    const _Float16* Kb = (const _Float16*)(lds + (cur << 13));
    const short*    Vt = (const short*)(lds + 16384);

    // ---- content scores, SWAPPED: sc[ct][r] = S[key=16ct+4q+r][q=16w+l15] ----
    f32x4 sc[4];
    __builtin_amdgcn_s_setprio(1);
#pragma unroll
    for (int ct = 0; ct < 4; ++ct) {
      f16x8 ka = *(const f16x8*)&Kb[swz(16*ct + l15, quad*8)];
      f16x8 kb = *(const f16x8*)&Kb[swz(16*ct + l15, 32 + quad*8)];
      f32x4 acc = (f32x4){NSHIFT, NSHIFT, NSHIFT, NSHIFT};
      acc = MFMA_F16(ka, quF[0], acc);        // A = K-frag, B = Q-frag
      acc = MFMA_F16(kb, quF[1], acc);
      sc[ct] = acc;
    }
    __builtin_amdgcn_s_setprio(0);

    // ---- ring gather + exp2 (swapped indexing) ----
    const int base = k0 - a0 - 16*wave;
    if (k0 == a0 || k0 == a0 + 64) {
      // general path (2/16 iters): per-element u / e==1 handling
      const int adA = (iQ >> 1) * 264 + (iQ & 1);                // u=0
      const int adB = ((iQ + 1) >> 1) * 264 + ((iQ + 1) & 1);    // u=1
#pragma unroll
      for (int ct = 0; ct < 4; ++ct) {
        const int e0 = base + 16*ct + 4*quad - l15;
#pragma unroll
        for (int r = 0; r < 4; ++r) {
          const int e    = e0 + r;
          const int u    = (e > 0) ? 1 : 0;
          const int slot = (e - 1 - u) & 127;
          float pos = (float)Pb2h[(u ? adB : adA) + 2*slot];
          float s   = sc[ct][r] + ((e == 1) ? 0.f : pos);
          sc[ct][r] = exp2fast(s);
        }
      }
    } else {
      // fast path: u uniform, 4 consecutive ring words per ct (mirrors absorb wrap)
      const int u  = (k0 > a0) ? 1 : 0;
      const int iu = iQ + u;
      const unsigned* wrow = &Pb2[(iu >> 1) * 132];
      const int sh = (iu & 1) << 4;
      const int sb = base - 1 - u + 4*quad - l15 + 2048;
#pragma unroll
      for (int ct = 0; ct < 4; ++ct) {
        const int s0 = (sb + 16*ct) & 127;
        unsigned w0 = wrow[s0];
        unsigned w1 = wrow[s0 + 1];
        unsigned w2 = wrow[s0 + 2];
        unsigned w3 = wrow[s0 + 3];
        sc[ct][0] = exp2fast(sc[ct][0] + h2f(w0, sh));
        sc[ct][1] = exp2fast(sc[ct][1] + h2f(w1, sh));
        sc[ct][2] = exp2fast(sc[ct][2] + h2f(w2, sh));
        sc[ct][3] = exp2fast(sc[ct][3] + h2f(w3, sh));
      }
    }

    // ---- PV straight from registers: 4x4 K=16 bf16 MFMAs + ones-l ----
    __builtin_amdgcn_s_setprio(1);
#pragma unroll
    for (int ctk = 0; ctk < 4; ++ctk) {
      unsigned lo = pkb2(sc[ctk][0], sc[ctk][1]);
      unsigned hi = pkb2(sc[ctk][2], sc[ctk][3]);
      b16x4 aF = __builtin_bit_cast(b16x4, (u32x2){lo, hi});
      acc_l = mfma16bf(aF, ONESB, acc_l);     // l partial (all cols equal)
#pragma unroll
      for (int ctd = 0; ctd < 4; ++ctd) {
        b16x4 bF = *(const b16x4*)&Vt[swzv(16*ctd + l15, 16*ctk + 4*quad)];
        Oacc[ctd] = mfma16bf(aF, bF, Oacc[ctd]);
      }
    }
    __builtin_amdgcn_s_setprio(0);

    if (!last) bandMFMA();            // next iter's 64 new ring cols (regs)
    cur ^= 1;
  }

  // ---- epilogue: O = Oacc / l, l in-lane from ones-MFMA ----
#pragma unroll
  for (int r = 0; r < 4; ++r) {
    float inv = 1.0f / acc_l[r];
    const size_t rowo = (size_t)n * SQ * HD + (size_t)(a0 + iiB + r) * HD;
#pragma unroll
    for (int ct = 0; ct < 4; ++ct)
      O[rowo + 16*ct + l15] = Oacc[ct][r] * inv;
  }
}

// ---------------- fallback (R3-style, raw inputs) for small ws ----------------

__global__ __launch_bounds__(256, 4) void relpos_sdpa_fb(
    const float* __restrict__ Q, const float* __restrict__ K,
    const float* __restrict__ V, const float* __restrict__ Ub,
    const float* __restrict__ Vb, const float* __restrict__ R,
    float* __restrict__ O)
{
  const int n    = blockIdx.x;
  const int h    = n & (NHD - 1);
  const int a0   = blockIdx.y * 64;
  const int tid  = threadIdx.x;
  const int lane = tid & 63, wave = tid >> 6;
  const int l15  = lane & 15, quad = lane >> 4;

  const float* Qn = Q + (size_t)n * SQ * HD;
  const float* Kn = K + (size_t)n * SQ * HD;
  const float* Vn = V + (size_t)n * SQ * HD;
  const float* Rh = R + (size_t)h * RMAX * HD;

  __shared__ __align__(16) char lds[38656];
  _Float16* Kb = (_Float16*)lds;
  short*    Ps = (short*)lds;
  short*    Vt = (short*)(lds + 9216);
  _Float16* Pb = (_Float16*)(lds + 9216 + 11520);

  f16x8 quF[2], qvF[5][2];
#pragma unroll
  for (int ks = 0; ks < 2; ++ks) {
    const int db = ks * 32 + quad * 8;
    float ub[8], vb[8];
#pragma unroll
    for (int j = 0; j < 8; ++j) { ub[j] = Ub[h*HD + db + j]; vb[j] = Vb[h*HD + db + j]; }
    {
      const float* p = Qn + (size_t)(a0 + 16*wave + l15) * HD + db;
      f16x8 f;
#pragma unroll
      for (int j = 0; j < 8; ++j) f[j] = (_Float16)(p[j] * 0.125f + ub[j]);
      quF[ks] = f;
    }
#pragma unroll
    for (int rt = 0; rt < 5; ++rt) {
      int row = a0 + 16*rt + l15; if (row > SQ-1) row = SQ-1;
      const float* p = Qn + (size_t)row * HD + db;
      f16x8 f;
#pragma unroll
      for (int j = 0; j < 8; ++j) f[j] = (_Float16)(p[j] * 0.125f + vb[j]);
      qvF[rt][ks] = f;
    }
  }

  if (tid < 64) Vt[64*72 + tid] = (short)0x3F80;

  f32x4 Oacc[5];
#pragma unroll
  for (int ct = 0; ct < 5; ++ct) Oacc[ct] = (f32x4){0.f, 0.f, 0.f, 0.f};

  auto band = [&](int jstart) {
    const int c    = jstart + 16*wave + l15;
    const int j    = (c + 2048) & (SQ - 1);
    const int slot = (c + 2048) & 127;
    const float* rp = Rh + (size_t)j * HD + quad * 8;
    f16x8 B0, B1;
    {
      float4 x0 = *(const float4*)(rp),      float4_x1 = *(const float4*)(rp + 4);
      float4 x1 = float4_x1;
      float4 y0 = *(const float4*)(rp + 32), y1 = *(const float4*)(rp + 36);
#pragma unroll
      for (int t = 0; t < 4; ++t) { B0[t] = (_Float16)(&x0.x)[t]; B0[t+4] = (_Float16)(&x1.x)[t]; }
#pragma unroll
      for (int t = 0; t < 4; ++t) { B1[t] = (_Float16)(&y0.x)[t]; B1[t+4] = (_Float16)(&y1.x)[t]; }
    }
#pragma unroll
    for (int rt = 0; rt < 5; ++rt) {
      f32x4 acc = (f32x4){0.f, 0.f, 0.f, 0.f};
      acc = MFMA_F16(qvF[rt][0], B0, acc);
      acc = MFMA_F16(qvF[rt][1], B1, acc);
      const int row = 16*rt + 4*quad;
      if (rt < 4) {
        *(unsigned*)&Pb[slot*70 + row]     = pkh(acc[0], acc[1]);
        *(unsigned*)&Pb[slot*70 + row + 2] = pkh(acc[2], acc[3]);
      } else if (quad == 0) {
        *(unsigned*)&Pb[slot*70 + row]     = pkh(acc[0], acc[1]);
      }
    }
  };

  band(-a0 - 65);
  band(-a0 - 1);

  const int sr = tid >> 2, sc4 = tid & 3;
  const int iiB = 16*wave + 4*quad;

  for (int k0 = 0; k0 < SQ; k0 += 64) {
    __syncthreads();
    {
      const float* src = Kn + (size_t)(k0 + sr) * HD + sc4 * 16;
      float4 x0 = *(const float4*)(src),     x1 = *(const float4*)(src + 4);
      float4 y0 = *(const float4*)(src + 8), y1 = *(const float4*)(src + 12);
      f16x8 lo, hi;
#pragma unroll
      for (int t = 0; t < 4; ++t) { lo[t] = (_Float16)(&x0.x)[t]; lo[t+4] = (_Float16)(&x1.x)[t]; }
#pragma unroll
      for (int t = 0; t < 4; ++t) { hi[t] = (_Float16)(&y0.x)[t]; hi[t+4] = (_Float16)(&y1.x)[t]; }
      *(f16x8*)&Kb[sr*72 + sc4*16]     = lo;
      *(f16x8*)&Kb[sr*72 + sc4*16 + 8] = hi;
    }
    {
      const int g = lane >> 3;
#pragma unroll
      for (int i = 0; i < 8; ++i) {
        int bp = 8*wave + (i ^ g);
        float v0 = Vn[(size_t)(k0 + 2*bp)     * HD + lane];
        float v1 = Vn[(size_t)(k0 + 2*bp + 1) * HD + lane];
        *(unsigned*)&Vt[lane*72 + 2*bp] = pkb2(v0, v1);
      }
    }
    __syncthreads();

    f32x4 sc[4];
#pragma unroll
    for (int ct = 0; ct < 4; ++ct) {
      f16x8 b0 = *(const f16x8*)&Kb[(16*ct + l15)*72 + quad*8];
      f16x8 b1 = *(const f16x8*)&Kb[(16*ct + l15)*72 + 32 + quad*8];
      f32x4 acc = (f32x4){0.f, 0.f, 0.f, 0.f};
      acc = MFMA_F16(quF[0], b0, acc);
      acc = MFMA_F16(quF[1], b1, acc);
      sc[ct] = acc;
    }

    const int dlt = k0 - a0;
#pragma unroll
    for (int r = 0; r < 4; ++r) {
      const int ii = iiB + r;
#pragma unroll
      for (int ct = 0; ct < 4; ++ct) {
        const int e    = dlt + 16*ct + l15 - ii;
        const int u    = (e > 0) ? 1 : 0;
        const int slot = (e - 1 - u + 2048) & 127;
        float pos = (float)Pb[slot*70 + ii + u];
        float s   = sc[ct][r] + ((e == 1) ? 0.f : pos);
        sc[ct][r] = __expf(s - 40.0f);
      }
    }
    __syncthreads();

#pragma unroll
    for (int r = 0; r < 4; ++r)
#pragma unroll
      for (int ct = 0; ct < 4; ++ct)
        Ps[(iiB + r)*68 + 16*ct + l15] = f2b(sc[ct][r]);

    b16x8 pA0 = *(const b16x8*)&Ps[(16*wave + l15)*68 + quad*8];
    b16x8 pA1 = *(const b16x8*)&Ps[(16*wave + l15)*68 + 32 + quad*8];
#pragma unroll
    for (int ct = 0; ct < 5; ++ct) {
      b16x8 v0 = *(const b16x8*)&Vt[(16*ct + l15)*72 + quad*8];
      b16x8 v1 = *(const b16x8*)&Vt[(16*ct + l15)*72 + 32 + quad*8];
      Oacc[ct] = MFMA_BF16(pA0, v0, Oacc[ct]);
      Oacc[ct] = MFMA_BF16(pA1, v1, Oacc[ct]);
    }

    if (k0 < SQ - 64) band(k0 + 64 - a0 - 1);
  }

#pragma unroll
  for (int r = 0; r < 4; ++r) {
    float l   = __shfl(Oacc[4][r], lane & 48);
    float inv = 1.0f / l;
    const size_t rowo = (size_t)n * SQ * HD + (size_t)(a0 + iiB + r) * HD;
#pragma unroll
    for (int ct = 0; ct < 4; ++ct)
      O[rowo + 16*ct + l15] = Oacc[ct][r] * inv;
  }
}

extern "C" void kernel_launch(void* const* d_in, const int* in_sizes, int n_in,
                              void* d_out, int out_size, void* d_ws, size_t ws_size,
                              hipStream_t stream) {
  const float* Q  = (const float*)d_in[0];
  const float* K  = (const float*)d_in[1];
  const float* V  = (const float*)d_in[2];
  const float* Ub = (const float*)d_in[3];  // (1,16,1,64)
  const float* Vb = (const float*)d_in[4];
  const float* R  = (const float*)d_in[5];  // (16,2048,64)
  float* O = (float*)d_out;

  if (ws_size >= WS_NEED) {
    _Float16* Kh  = (_Float16*)((char*)d_ws + KH_OFF);
    short*    Vt  = (short*)((char*)d_ws + VT_OFF);
    _Float16* R16 = (_Float16*)((char*)d_ws + R16_OFF);

    preprep<<<6144, 256, 0, stream>>>(K, R, V, Kh, R16, Vt);

    dim3 grid(64, 16);   // x = n (XCD locality), y = q-tile
    relpos_sdpa_r21<<<grid, 256, 0, stream>>>(Q, Kh, Vt, R16, Ub, Vb, O);
  } else {
    dim3 grid(64, 16);
    relpos_sdpa_fb<<<grid, 256, 0, stream>>>(Q, K, V, Ub, Vb, R, O);
  }
}

// Round 15
// 166.088 us; speedup vs baseline: 1.0475x; 1.0475x over previous
//
#include <hip/hip_runtime.h>

// RelativePositionSDPA — R22: restore the champion (R17/R20), final.
//
// R21 post-mortem (branch b): LDS 42.5K still gave 2 blocks/CU at VGPR 84 —
// 3x42496=127488 fits any plausible pool, so the occupancy pin is
// register/AGPR-side (VGPR 84 + ~36 AGPR > 128/lane -> 2 waves/SIMD
// granule). Single-buffered V cost ~18us of exposed DMA latency. Reverted.
//
// Exhausted levers at 2 blocks/CU: occupancy (LDS shrink x3, launch-bounds
// x2, reg diet) — all pinned; micro-opts (batched gather, setprio alone,
// gather hoist, RTZ pack) — all null; staging removal (R10 L2-operands,
// R19 K-in-regs) — both regress. Champion equilibrium: main 77us,
// MfmaUtil ~21%, VALU ~39%, HBM ~6%, conflicts ~2%.
//
// Champion structure:
//  - Kb/Vt staged via __builtin_amdgcn_global_load_lds width=16: linear LDS
//    dest + pre-swizzled per-lane GLOBAL source (m173); Vt half-XOR baked
//    into ws by preprep.
//  - Double-buffered Kb/Vt + raw s_barrier with counted vmcnt(6) (never 0
//    mid-loop); sched_barrier(0) fences pin issue order.
//  - Swapped-operand QK^T (S^T in regs), PV as 4x4 K=16 bf16 MFMAs straight
//    from registers, ones-B MFMA for l (in-lane epilogue).
//  - Batched ring gather (4 consecutive u32/ct, mirror cols absorb wrap),
//    band split load/MFMA, deferred ring flush, setprio, C-init softmax
//    shift, exp2 domain, RTN f16 ring pack.
//
// Session: total 189.9 -> 166.5us (main 102 -> 77us, -25%).
// Ladder: R7 102 -> R11 92.4 (swizzle+fastpath+prefetch) -> R14 87.7
// (Ps eliminated via swapped QK) -> R15 82.8 (PV conflict fix) -> R17 77.0
// (DMA staging + counted vmcnt).

#define SQ    1024
#define HD    64
#define NHD   16
#define RMAX  2048

typedef _Float16 f16x8 __attribute__((ext_vector_type(8)));
typedef _Float16 f16x4 __attribute__((ext_vector_type(4)));
typedef short    b16x8 __attribute__((ext_vector_type(8)));
typedef short    b16x4 __attribute__((ext_vector_type(4)));
typedef float    f32x4 __attribute__((ext_vector_type(4)));
typedef unsigned u32x2 __attribute__((ext_vector_type(2)));
typedef unsigned u32x4 __attribute__((ext_vector_type(4)));

#define MFMA_F16(A,B,C)  __builtin_amdgcn_mfma_f32_16x16x32_f16((A),(B),(C),0,0,0)
#define MFMA_BF16(A,B,C) __builtin_amdgcn_mfma_f32_16x16x32_bf16((A),(B),(C),0,0,0)

#define L2E    1.44269504088896f    // log2(e)
#define NSHIFT (-57.7078016f)       // -40 * log2(e)

// ws layout
#define KH_OFF   0                       // f16 [64][1024][64]   8 MB
#define VT_OFF   (8u << 20)              // bf16 [64][80][1024]  10 MB (half-XOR'd rows)
#define R16_OFF  (18u << 20)             // f16 [16][1024][64]   2 MB
#define WS_NEED  (20u << 20)

__device__ __forceinline__ float exp2fast(float x) {
#if __has_builtin(__builtin_amdgcn_exp2f)
  return __builtin_amdgcn_exp2f(x);          // v_exp_f32 (2^x native)
#else
  return __expf(x * 0.693147180559945f);
#endif
}

// K=16 bf16 MFMA; zero-padded K=32 fallback is mathematically identical.
__device__ __forceinline__ f32x4 mfma16bf(b16x4 a, b16x4 b, f32x4 c) {
#if __has_builtin(__builtin_amdgcn_mfma_f32_16x16x16bf16_1k)
  return __builtin_amdgcn_mfma_f32_16x16x16bf16_1k(a, b, c, 0, 0, 0);
#else
  b16x8 az = {a[0], a[1], a[2], a[3], 0, 0, 0, 0};
  b16x8 bz = {b[0], b[1], b[2], b[3], 0, 0, 0, 0};
  return MFMA_BF16(az, bz, c);
#endif
}

__device__ __forceinline__ short f2b(float f) {          // fp32 -> bf16 RTN-even
  unsigned u = __builtin_bit_cast(unsigned, f);
  u += 0x7FFFu + ((u >> 16) & 1u);
  return (short)(u >> 16);
}
// 2xf32 -> packed f16 RTN (scalar casts; champion numerics)
__device__ __forceinline__ unsigned pkh(float a, float b) {
  _Float16 h0 = (_Float16)a, h1 = (_Float16)b;
  return (unsigned)__builtin_bit_cast(unsigned short, h0)
       | ((unsigned)__builtin_bit_cast(unsigned short, h1) << 16);
}
// 2xf32 -> packed bf16, round-half-away (differs from RTN-even only on ties)
__device__ __forceinline__ unsigned pkb2(float a, float b) {
  unsigned ua = __builtin_bit_cast(unsigned, a) + 0x8000u;
  unsigned ub = __builtin_bit_cast(unsigned, b) + 0x8000u;
  return (ub & 0xFFFF0000u) | (ua >> 16);
}
// f16 half (sh=0 lo, sh=16 hi) of a packed u32 -> float
__device__ __forceinline__ float h2f(unsigned w, int sh) {
  return (float)__builtin_bit_cast(_Float16, (unsigned short)(w >> sh));
}
// XOR-swizzled element address inside a [rows][64] 2B-elem tile (Kb).
__device__ __forceinline__ int swz(int row, int col) {
  return row*64 + ((((col >> 3) ^ row) & 7) << 3) + (col & 7);
}
// Vt variant: + half-XOR with row bit3 (conflict-free b64 PV reads).
__device__ __forceinline__ int swzv(int row, int col) {
  return row*64 + ((((col >> 3) ^ row) & 7) << 3)
       + ((col & 7) ^ ((row & 8) >> 1));
}

// ---------------- merged precompute kernel ----------------
// Vt ws rows stored with half-XOR baked in (u32-granular ^4 on rows with
// bit3) so the main kernel's 16B DMA chunks deposit swzv() order directly.

__global__ __launch_bounds__(256) void preprep(
    const float* __restrict__ K, const float* __restrict__ R,
    const float* __restrict__ V,
    _Float16* __restrict__ Kh, _Float16* __restrict__ R16,
    short* __restrict__ Vt)
{
  __shared__ float t[64][65];
  const int bid = blockIdx.x, tid = threadIdx.x;
  if (bid < 1024) {
    const int n = bid >> 4, st = bid & 15;
    {
      const int row = tid >> 2, c0 = (tid & 3) * 16;
      const float* src = V + ((size_t)n * SQ + st * 64 + row) * HD + c0;
#pragma unroll
      for (int i = 0; i < 4; ++i) {
        float4 x = ((const float4*)src)[i];
        t[row][c0 + 4*i + 0] = x.x; t[row][c0 + 4*i + 1] = x.y;
        t[row][c0 + 4*i + 2] = x.z; t[row][c0 + 4*i + 3] = x.w;
      }
    }
    __syncthreads();
    {
      const int d = tid >> 2, s0 = (tid & 3) * 16;
      const int xo = (d & 8) ? 4 : 0;                 // half-XOR baked into ws
      short* dst = Vt + ((size_t)n * 80 + d) * SQ + st * 64 + s0;
#pragma unroll
      for (int i = 0; i < 8; ++i)
        *(unsigned*)(dst + (2*i ^ xo)) = pkb2(t[s0 + 2*i][d], t[s0 + 2*i + 1][d]);
    }
    if (tid < 64) {          // rows 64..79 unused by main; kept harmless
      const int s = st * 64 + tid;
      Vt[((size_t)n * 80 + 64) * SQ + s] = (short)0x3F80;
#pragma unroll
      for (int r = 65; r < 80; ++r) Vt[((size_t)n * 80 + r) * SQ + s] = 0;
    }
  } else {
    const int idx = (bid - 1024) * 256 + tid;            // float4 index
    const int nk4 = (64 * SQ * HD) / 4;                  // 1048576
    if (idx < nk4) {
      float4 v = ((const float4*)K)[idx];
      f16x4 o = { (_Float16)v.x, (_Float16)v.y, (_Float16)v.z, (_Float16)v.w };
      *(f16x4*)(Kh + 4 * (size_t)idx) = o;
    } else {
      int rr = idx - nk4;                                // < 262144
      int h  = rr >> 14, off = rr & 16383;               // 16384 float4/head
      float4 v = ((const float4*)R)[((size_t)h << 15) + off];
      f16x4 o = { (_Float16)v.x, (_Float16)v.y, (_Float16)v.z, (_Float16)v.w };
      *(f16x4*)(R16 + 4 * (((size_t)h << 14) + off)) = o;
    }
  }
}

// ---------------- main flash kernel (R22 = R17/R20 champion) ----------------

__global__ __launch_bounds__(256, 3) void relpos_sdpa_r22(
    const float* __restrict__ Q, const _Float16* __restrict__ Kh,
    const short* __restrict__ Vtg, const _Float16* __restrict__ R16,
    const float* __restrict__ Ub, const float* __restrict__ Vb,
    float* __restrict__ O)
{
  const int n    = blockIdx.x;
  const int h    = n & (NHD - 1);
  const int a0   = blockIdx.y * 64;
  const int tid  = threadIdx.x;
  const int lane = tid & 63, wave = tid >> 6;
  const int l15  = lane & 15, quad = lane >> 4;

  const float*    Qn  = Q   + (size_t)n * SQ * HD;
  const _Float16* Khn = Kh  + (size_t)n * SQ * HD;
  const short*    Vgn = Vtg + (size_t)n * 80 * SQ;
  const _Float16* Rh  = R16 + (size_t)h * SQ * HD;

  // LDS: Kb f16 [2][64][64] swz   @ 0      (2 x 8192)
  //      Vt bf16 [2][64][64] swzv @ 16384  (2 x 8192)
  //      ring u32 [33][132]       @ 32768  (17424; cols 128..130 mirror 0..2)
  __shared__ __align__(16) char lds[50192];
  unsigned*       Pb2  = (unsigned*)(lds + 32768);
  const _Float16* Pb2h = (const _Float16*)Pb2;

  // DMA: linear LDS dest (slot = lane + 64*(2w+i)), pre-swizzled global src.
  auto gload16 = [&](const void* g, void* l) {
#if __has_builtin(__builtin_amdgcn_global_load_lds)
    __builtin_amdgcn_global_load_lds(
        (const __attribute__((address_space(1))) unsigned*)g,
        (__attribute__((address_space(3))) unsigned*)l, 16, 0, 0);
#else
    *(u32x4*)((char*)l + lane * 16) = *(const u32x4*)g;   // reg round-trip
#endif
  };
  auto dmaStage = [&](int kk, int buf) {
    const int rb = lane >> 3;
    const int g  = (lane & 7) ^ ((lane >> 3) & 7);
    char* kdst = lds + buf * 8192;
    char* vdst = lds + 16384 + buf * 8192;
#pragma unroll
    for (int i = 0; i < 2; ++i) {
      const int sub = 2*wave + i;
      const int r   = 8*sub + rb;
      gload16(Khn + (size_t)(kk + r) * HD + 8*g, kdst + sub * 1024);
      gload16(Vgn + (size_t)r * SQ + kk + 8*g,   vdst + sub * 1024);
    }
  };

  dmaStage(0, 0);   // tile 0 in flight under the whole prologue

  // ---- persistent q fragments, pre-scaled by log2(e) ----
  f16x8 quF[2], qvF[5][2];
#pragma unroll
  for (int ks = 0; ks < 2; ++ks) {
    const int db = ks * 32 + quad * 8;
    float ub[8], vb[8];
#pragma unroll
    for (int j = 0; j < 8; ++j) {
      ub[j] = Ub[h*HD + db + j] * L2E;
      vb[j] = Vb[h*HD + db + j] * L2E;
    }
    {
      const float* p = Qn + (size_t)(a0 + 16*wave + l15) * HD + db;
      float4 x0 = ((const float4*)p)[0], x1 = ((const float4*)p)[1];
      f16x8 f;
#pragma unroll
      for (int t = 0; t < 4; ++t) {
        f[t]   = (_Float16)((&x0.x)[t] * (0.125f * L2E) + ub[t]);
        f[t+4] = (_Float16)((&x1.x)[t] * (0.125f * L2E) + ub[t+4]);
      }
      quF[ks] = f;
    }
#pragma unroll
    for (int rt = 0; rt < 5; ++rt) {
      int row = a0 + 16*rt + l15; if (row > SQ-1) row = SQ-1;
      const float* p = Qn + (size_t)row * HD + db;
      float4 x0 = ((const float4*)p)[0], x1 = ((const float4*)p)[1];
      f16x8 f;
#pragma unroll
      for (int t = 0; t < 4; ++t) {
        f[t]   = (_Float16)((&x0.x)[t] * (0.125f * L2E) + vb[t]);
        f[t+4] = (_Float16)((&x1.x)[t] * (0.125f * L2E) + vb[t+4]);
      }
      qvF[rt][ks] = f;
    }
  }

  f32x4 Oacc[4], acc_l;
#pragma unroll
  for (int ct = 0; ct < 4; ++ct) Oacc[ct] = (f32x4){0.f, 0.f, 0.f, 0.f};
  acc_l = (f32x4){0.f, 0.f, 0.f, 0.f};

  const b16x4 ONESB = {(short)0x3F80, (short)0x3F80, (short)0x3F80, (short)0x3F80};

  // ---- band, split: bandLoad (issue R16 loads early) / bandMFMA (compute) ----
  unsigned ringW[9];
  int ringSlot, ringSlotN;
  f16x8 bB0, bB1;
  auto bandLoad = [&](int jstart) {
    const int c = jstart + 16*wave + l15;
    const int j = (c + 2048) & (SQ - 1);
    ringSlotN   = (c + 2048) & 127;
    const _Float16* rp = Rh + (size_t)j * HD + quad * 8;
    bB0 = *(const f16x8*)rp;
    bB1 = *(const f16x8*)(rp + 32);
  };
  auto bandMFMA = [&]() {
    ringSlot = ringSlotN;
    __builtin_amdgcn_s_setprio(1);
#pragma unroll
    for (int rt = 0; rt < 5; ++rt) {
      f32x4 acc = (f32x4){0.f, 0.f, 0.f, 0.f};
      acc = MFMA_F16(qvF[rt][0], bB0, acc);
      acc = MFMA_F16(qvF[rt][1], bB1, acc);
      if (rt < 4) {
        ringW[2*rt]     = pkh(acc[0], acc[1]);
        ringW[2*rt + 1] = pkh(acc[2], acc[3]);
      } else {
        ringW[8] = pkh(acc[0], acc[1]);   // row 64 (only quad 0's used)
      }
    }
    __builtin_amdgcn_s_setprio(0);
  };
  auto ringFlush = [&]() {
#pragma unroll
    for (int rt = 0; rt < 4; ++rt) {
      const int rp0 = 8*rt + 2*quad;                 // rows 16rt+4q .. +3
      Pb2[rp0*132 + ringSlot]       = ringW[2*rt];
      Pb2[(rp0 + 1)*132 + ringSlot] = ringW[2*rt + 1];
    }
    if (quad == 0) Pb2[32*132 + ringSlot] = ringW[8];
    if (ringSlot < 3) {                              // mirror cols 128..130
      const int ms = ringSlot + 128;
#pragma unroll
      for (int rt = 0; rt < 4; ++rt) {
        const int rp0 = 8*rt + 2*quad;
        Pb2[rp0*132 + ms]       = ringW[2*rt];
        Pb2[(rp0 + 1)*132 + ms] = ringW[2*rt + 1];
      }
      if (quad == 0) Pb2[32*132 + ms] = ringW[8];
    }
  };

  // prologue: fill all 128 ring slots for iter 0 (pre-loop, no races)
  bandLoad(-a0 - 65);  bandMFMA();  ringFlush();
  bandLoad(-a0 - 1);   bandMFMA();  ringFlush();

  const int iiB = 16*wave + 4*quad;
  const int iQ  = 16*wave + l15;          // this lane's q-local row (swapped)

  int cur = 0;
  for (int k0 = 0; k0 < SQ; k0 += 64) {
    // ---- barrier A: prev compute's LDS reads + ring gathers done ----
    __builtin_amdgcn_sched_barrier(0);
    asm volatile("s_waitcnt lgkmcnt(0)" ::: "memory");
    __builtin_amdgcn_s_barrier();
    __builtin_amdgcn_sched_barrier(0);

    if (k0 > 0) ringFlush();          // ring cols from prev iter's bandMFMA
    if (k0 < SQ - 64) {
      bandLoad(k0 + 64 - a0 - 1);     // 2 vmem (for this iter's bandMFMA)
      dmaStage(k0 + 64, cur ^ 1);     // 4 vmem -> other buffer
      __builtin_amdgcn_sched_barrier(0);
      asm volatile("s_waitcnt vmcnt(6) lgkmcnt(0)" ::: "memory");  // tile k0 done
    } else {
      __builtin_amdgcn_sched_barrier(0);
      asm volatile("s_waitcnt vmcnt(0) lgkmcnt(0)" ::: "memory");
    }
    // ---- barrier B: Kb/Vt[cur] staged + ring visible ----
    __builtin_amdgcn_s_barrier();
    __builtin_amdgcn_sched_barrier(0);

    const _Float16* Kb = (const _Float16*)(lds + (cur << 13));
    const short*    Vt = (const short*)(lds + 16384 + (cur << 13));

    // ---- content scores, SWAPPED: sc[ct][r] = S[key=16ct+4q+r][q=16w+l15] ----
    f32x4 sc[4];
    __builtin_amdgcn_s_setprio(1);
#pragma unroll
    for (int ct = 0; ct < 4; ++ct) {
      f16x8 ka = *(const f16x8*)&Kb[swz(16*ct + l15, quad*8)];
      f16x8 kb = *(const f16x8*)&Kb[swz(16*ct + l15, 32 + quad*8)];
      f32x4 acc = (f32x4){NSHIFT, NSHIFT, NSHIFT, NSHIFT};
      acc = MFMA_F16(ka, quF[0], acc);        // A = K-frag, B = Q-frag
      acc = MFMA_F16(kb, quF[1], acc);
      sc[ct] = acc;
    }
    __builtin_amdgcn_s_setprio(0);

    // ---- ring gather + exp2 (swapped indexing) ----
    const int base = k0 - a0 - 16*wave;
    if (k0 == a0 || k0 == a0 + 64) {
      // general path (2/16 iters): per-element u / e==1 handling
      const int adA = (iQ >> 1) * 264 + (iQ & 1);                // u=0
      const int adB = ((iQ + 1) >> 1) * 264 + ((iQ + 1) & 1);    // u=1
#pragma unroll
      for (int ct = 0; ct < 4; ++ct) {
        const int e0 = base + 16*ct + 4*quad - l15;
#pragma unroll
        for (int r = 0; r < 4; ++r) {
          const int e    = e0 + r;
          const int u    = (e > 0) ? 1 : 0;
          const int slot = (e - 1 - u) & 127;
          float pos = (float)Pb2h[(u ? adB : adA) + 2*slot];
          float s   = sc[ct][r] + ((e == 1) ? 0.f : pos);
          sc[ct][r] = exp2fast(s);
        }
      }
    } else {
      // fast path: u uniform, 4 consecutive ring words per ct (mirrors absorb wrap)
      const int u  = (k0 > a0) ? 1 : 0;
      const int iu = iQ + u;
      const unsigned* wrow = &Pb2[(iu >> 1) * 132];
      const int sh = (iu & 1) << 4;
      const int sb = base - 1 - u + 4*quad - l15 + 2048;
#pragma unroll
      for (int ct = 0; ct < 4; ++ct) {
        const int s0 = (sb + 16*ct) & 127;
        unsigned w0 = wrow[s0];
        unsigned w1 = wrow[s0 + 1];
        unsigned w2 = wrow[s0 + 2];
        unsigned w3 = wrow[s0 + 3];
        sc[ct][0] = exp2fast(sc[ct][0] + h2f(w0, sh));
        sc[ct][1] = exp2fast(sc[ct][1] + h2f(w1, sh));
        sc[ct][2] = exp2fast(sc[ct][2] + h2f(w2, sh));
        sc[ct][3] = exp2fast(sc[ct][3] + h2f(w3, sh));
      }
    }

    // ---- PV straight from registers: 4x4 K=16 bf16 MFMAs + ones-l ----
    __builtin_amdgcn_s_setprio(1);
#pragma unroll
    for (int ctk = 0; ctk < 4; ++ctk) {
      unsigned lo = pkb2(sc[ctk][0], sc[ctk][1]);
      unsigned hi = pkb2(sc[ctk][2], sc[ctk][3]);
      b16x4 aF = __builtin_bit_cast(b16x4, (u32x2){lo, hi});
      acc_l = mfma16bf(aF, ONESB, acc_l);     // l partial (all cols equal)
#pragma unroll
      for (int ctd = 0; ctd < 4; ++ctd) {
        b16x4 bF = *(const b16x4*)&Vt[swzv(16*ctd + l15, 16*ctk + 4*quad)];
        Oacc[ctd] = mfma16bf(aF, bF, Oacc[ctd]);
      }
    }
    __builtin_amdgcn_s_setprio(0);

    if (k0 < SQ - 64) bandMFMA();     // next iter's 64 new ring cols (regs)
    cur ^= 1;
  }

  // ---- epilogue: O = Oacc / l, l in-lane from ones-MFMA ----
#pragma unroll
  for (int r = 0; r < 4; ++r) {
    float inv = 1.0f / acc_l[r];
    const size_t rowo = (size_t)n * SQ * HD + (size_t)(a0 + iiB + r) * HD;
#pragma unroll
    for (int ct = 0; ct < 4; ++ct)
      O[rowo + 16*ct + l15] = Oacc[ct][r] * inv;
  }
}

// ---------------- fallback (R3-style, raw inputs) for small ws ----------------

__global__ __launch_bounds__(256, 4) void relpos_sdpa_fb(
    const float* __restrict__ Q, const float* __restrict__ K,
    const float* __restrict__ V, const float* __restrict__ Ub,
    const float* __restrict__ Vb, const float* __restrict__ R,
    float* __restrict__ O)
{
  const int n    = blockIdx.x;
  const int h    = n & (NHD - 1);
  const int a0   = blockIdx.y * 64;
  const int tid  = threadIdx.x;
  const int lane = tid & 63, wave = tid >> 6;
  const int l15  = lane & 15, quad = lane >> 4;

  const float* Qn = Q + (size_t)n * SQ * HD;
  const float* Kn = K + (size_t)n * SQ * HD;
  const float* Vn = V + (size_t)n * SQ * HD;
  const float* Rh = R + (size_t)h * RMAX * HD;

  __shared__ __align__(16) char lds[38656];
  _Float16* Kb = (_Float16*)lds;
  short*    Ps = (short*)lds;
  short*    Vt = (short*)(lds + 9216);
  _Float16* Pb = (_Float16*)(lds + 9216 + 11520);

  f16x8 quF[2], qvF[5][2];
#pragma unroll
  for (int ks = 0; ks < 2; ++ks) {
    const int db = ks * 32 + quad * 8;
    float ub[8], vb[8];
#pragma unroll
    for (int j = 0; j < 8; ++j) { ub[j] = Ub[h*HD + db + j]; vb[j] = Vb[h*HD + db + j]; }
    {
      const float* p = Qn + (size_t)(a0 + 16*wave + l15) * HD + db;
      f16x8 f;
#pragma unroll
      for (int j = 0; j < 8; ++j) f[j] = (_Float16)(p[j] * 0.125f + ub[j]);
      quF[ks] = f;
    }
#pragma unroll
    for (int rt = 0; rt < 5; ++rt) {
      int row = a0 + 16*rt + l15; if (row > SQ-1) row = SQ-1;
      const float* p = Qn + (size_t)row * HD + db;
      f16x8 f;
#pragma unroll
      for (int j = 0; j < 8; ++j) f[j] = (_Float16)(p[j] * 0.125f + vb[j]);
      qvF[rt][ks] = f;
    }
  }

  if (tid < 64) Vt[64*72 + tid] = (short)0x3F80;

  f32x4 Oacc[5];
#pragma unroll
  for (int ct = 0; ct < 5; ++ct) Oacc[ct] = (f32x4){0.f, 0.f, 0.f, 0.f};

  auto band = [&](int jstart) {
    const int c    = jstart + 16*wave + l15;
    const int j    = (c + 2048) & (SQ - 1);
    const int slot = (c + 2048) & 127;
    const float* rp = Rh + (size_t)j * HD + quad * 8;
    f16x8 B0, B1;
    {
      float4 x0 = *(const float4*)(rp),      x1 = *(const float4*)(rp + 4);
      float4 y0 = *(const float4*)(rp + 32), y1 = *(const float4*)(rp + 36);
#pragma unroll
      for (int t = 0; t < 4; ++t) { B0[t] = (_Float16)(&x0.x)[t]; B0[t+4] = (_Float16)(&x1.x)[t]; }
#pragma unroll
      for (int t = 0; t < 4; ++t) { B1[t] = (_Float16)(&y0.x)[t]; B1[t+4] = (_Float16)(&y1.x)[t]; }
    }
#pragma unroll
    for (int rt = 0; rt < 5; ++rt) {
      f32x4 acc = (f32x4){0.f, 0.f, 0.f, 0.f};
      acc = MFMA_F16(qvF[rt][0], B0, acc);
      acc = MFMA_F16(qvF[rt][1], B1, acc);
      const int row = 16*rt + 4*quad;
      if (rt < 4) {
        *(unsigned*)&Pb[slot*70 + row]     = pkh(acc[0], acc[1]);
        *(unsigned*)&Pb[slot*70 + row + 2] = pkh(acc[2], acc[3]);
      } else if (quad == 0) {
        *(unsigned*)&Pb[slot*70 + row]     = pkh(acc[0], acc[1]);
      }
    }
  };

  band(-a0 - 65);
  band(-a0 - 1);

  const int sr = tid >> 2, sc4 = tid & 3;
  const int iiB = 16*wave + 4*quad;

  for (int k0 = 0; k0 < SQ; k0 += 64) {
    __syncthreads();
    {
      const float* src = Kn + (size_t)(k0 + sr) * HD + sc4 * 16;
      float4 x0 = *(const float4*)(src),     x1 = *(const float4*)(src + 4);
      float4 y0 = *(const float4*)(src + 8), y1 = *(const float4*)(src + 12);
      f16x8 lo, hi;
#pragma unroll
      for (int t = 0; t < 4; ++t) { lo[t] = (_Float16)(&x0.x)[t]; lo[t+4] = (_Float16)(&x1.x)[t]; }
#pragma unroll
      for (int t = 0; t < 4; ++t) { hi[t] = (_Float16)(&y0.x)[t]; hi[t+4] = (_Float16)(&y1.x)[t]; }
      *(f16x8*)&Kb[sr*72 + sc4*16]     = lo;
      *(f16x8*)&Kb[sr*72 + sc4*16 + 8] = hi;
    }
    {
      const int g = lane >> 3;
#pragma unroll
      for (int i = 0; i < 8; ++i) {
        int bp = 8*wave + (i ^ g);
        float v0 = Vn[(size_t)(k0 + 2*bp)     * HD + lane];
        float v1 = Vn[(size_t)(k0 + 2*bp + 1) * HD + lane];
        *(unsigned*)&Vt[lane*72 + 2*bp] = pkb2(v0, v1);
      }
    }
    __syncthreads();

    f32x4 sc[4];
#pragma unroll
    for (int ct = 0; ct < 4; ++ct) {
      f16x8 b0 = *(const f16x8*)&Kb[(16*ct + l15)*72 + quad*8];
      f16x8 b1 = *(const f16x8*)&Kb[(16*ct + l15)*72 + 32 + quad*8];
      f32x4 acc = (f32x4){0.f, 0.f, 0.f, 0.f};
      acc = MFMA_F16(quF[0], b0, acc);
      acc = MFMA_F16(quF[1], b1, acc);
      sc[ct] = acc;
    }

    const int dlt = k0 - a0;
#pragma unroll
    for (int r = 0; r < 4; ++r) {
      const int ii = iiB + r;
#pragma unroll
      for (int ct = 0; ct < 4; ++ct) {
        const int e    = dlt + 16*ct + l15 - ii;
        const int u    = (e > 0) ? 1 : 0;
        const int slot = (e - 1 - u + 2048) & 127;
        float pos = (float)Pb[slot*70 + ii + u];
        float s   = sc[ct][r] + ((e == 1) ? 0.f : pos);
        sc[ct][r] = __expf(s - 40.0f);
      }
    }
    __syncthreads();

#pragma unroll
    for (int r = 0; r < 4; ++r)
#pragma unroll
      for (int ct = 0; ct < 4; ++ct)
        Ps[(iiB + r)*68 + 16*ct + l15] = f2b(sc[ct][r]);

    b16x8 pA0 = *(const b16x8*)&Ps[(16*wave + l15)*68 + quad*8];
    b16x8 pA1 = *(const b16x8*)&Ps[(16*wave + l15)*68 + 32 + quad*8];
#pragma unroll
    for (int ct = 0; ct < 5; ++ct) {
      b16x8 v0 = *(const b16x8*)&Vt[(16*ct + l15)*72 + quad*8];
      b16x8 v1 = *(const b16x8*)&Vt[(16*ct + l15)*72 + 32 + quad*8];
      Oacc[ct] = MFMA_BF16(pA0, v0, Oacc[ct]);
      Oacc[ct] = MFMA_BF16(pA1, v1, Oacc[ct]);
    }

    if (k0 < SQ - 64) band(k0 + 64 - a0 - 1);
  }

#pragma unroll
  for (int r = 0; r < 4; ++r) {
    float l   = __shfl(Oacc[4][r], lane & 48);
    float inv = 1.0f / l;
    const size_t rowo = (size_t)n * SQ * HD + (size_t)(a0 + iiB + r) * HD;
#pragma unroll
    for (int ct = 0; ct < 4; ++ct)
      O[rowo + 16*ct + l15] = Oacc[ct][r] * inv;
  }
}

extern "C" void kernel_launch(void* const* d_in, const int* in_sizes, int n_in,
                              void* d_out, int out_size, void* d_ws, size_t ws_size,
                              hipStream_t stream) {
  const float* Q  = (const float*)d_in[0];
  const float* K  = (const float*)d_in[1];
  const float* V  = (const float*)d_in[2];
  const float* Ub = (const float*)d_in[3];  // (1,16,1,64)
  const float* Vb = (const float*)d_in[4];
  const float* R  = (const float*)d_in[5];  // (16,2048,64)
  float* O = (float*)d_out;

  if (ws_size >= WS_NEED) {
    _Float16* Kh  = (_Float16*)((char*)d_ws + KH_OFF);
    short*    Vt  = (short*)((char*)d_ws + VT_OFF);
    _Float16* R16 = (_Float16*)((char*)d_ws + R16_OFF);

    preprep<<<6144, 256, 0, stream>>>(K, R, V, Kh, R16, Vt);

    dim3 grid(64, 16);   // x = n (XCD locality), y = q-tile
    relpos_sdpa_r22<<<grid, 256, 0, stream>>>(Q, Kh, Vt, R16, Ub, Vb, O);
  } else {
    dim3 grid(64, 16);
    relpos_sdpa_fb<<<grid, 256, 0, stream>>>(Q, K, V, Ub, Vb, R, O);
  }
}